// Round 2
// baseline (148.384 us; speedup 1.0000x reference)
//
#include <hip/hip_runtime.h>

// AlphaCompositor: fragments (N,K,H,W) int32 indices (-1 = empty),
// alphas (N,K,H,W) f32, ptclds (C,P) f32 -> images (N,C,H,W) f32.
// N=4 K=8 H=W=256 C=32 P=200000.

#define N_  4
#define K_  8
#define H_  256
#define W_  256
#define C_  32
#define P_  200000
#define HW_ (H_ * W_)

// ---------------------------------------------------------------------------
// Kernel 1: transpose ptclds (C,P) -> (P,C) so each point's 32 features are
// one contiguous 128 B chunk. Classic LDS tile transpose, 32x32 tiles.
// P = 200000 = 6250 * 32 exactly.
// ---------------------------------------------------------------------------
__global__ __launch_bounds__(256) void transpose_ptclds_kernel(
    const float* __restrict__ src,   // (C_, P_)
    float*       __restrict__ dst)   // (P_, C_)
{
    __shared__ float tile[32][33];   // +1 pad: bank-conflict-free transpose
    const int p0 = blockIdx.x * 32;
    const int tx = threadIdx.x;      // 0..31
    const int ty = threadIdx.y;      // 0..7

#pragma unroll
    for (int r = 0; r < 4; ++r) {
        const int c = ty + r * 8;
        tile[c][tx] = src[(size_t)c * P_ + p0 + tx];   // coalesced along P
    }
    __syncthreads();
#pragma unroll
    for (int r = 0; r < 4; ++r) {
        const int pl = ty + r * 8;
        // 32 consecutive c (=tx) -> contiguous 128B row write, coalesced
        dst[(size_t)(p0 + pl) * C_ + tx] = tile[tx][pl];
    }
}

// ---------------------------------------------------------------------------
// Kernel 2: composite. One thread per output pixel (n,h,w).
// TRANSPOSED=true: gather 128B contiguous per (pixel,k) from (P,C) table.
// TRANSPOSED=false: fallback gather from original (C,P) layout.
// ---------------------------------------------------------------------------
template <bool TRANSPOSED>
__global__ __launch_bounds__(256) void composite_kernel(
    const int*   __restrict__ frags,   // (N,K,H,W)
    const float* __restrict__ alphas,  // (N,K,H,W)
    const float* __restrict__ pt,      // (P,C) if TRANSPOSED else (C,P)
    float*       __restrict__ out)     // (N,C,H,W)
{
    const int tid = blockIdx.x * blockDim.x + threadIdx.x;  // 0 .. N*HW-1
    const int n  = tid >> 16;          // HW_ == 65536
    const int hw = tid & (HW_ - 1);
    const int base = n * K_ * HW_ + hw;

    // Load 8 indices + 8 alphas (each k-plane read is wave-coalesced).
    int   idx[K_];
    float al[K_];
#pragma unroll
    for (int k = 0; k < K_; ++k) idx[k] = frags[base + k * HW_];
#pragma unroll
    for (int k = 0; k < K_; ++k) al[k] = alphas[base + k * HW_];

    // Exclusive-transmittance compositing weights (sequential over K=8).
    float w[K_];
    float T = 1.0f;
#pragma unroll
    for (int k = 0; k < K_; ++k) {
        const bool valid = idx[k] >= 0;
        const float a = valid ? al[k] : 0.0f;
        w[k] = a * T;
        T *= (1.0f - a);
        if (!valid) idx[k] = 0;   // safe gather index; weight is 0
    }

    // 32-channel accumulator in registers (all indices compile-time after
    // full unroll -> stays in VGPRs, no scratch).
    float4 acc[8];
#pragma unroll
    for (int i = 0; i < 8; ++i) acc[i] = make_float4(0.f, 0.f, 0.f, 0.f);

    if (TRANSPOSED) {
#pragma unroll
        for (int k = 0; k < K_; ++k) {
            const float4* f =
                reinterpret_cast<const float4*>(pt + (size_t)idx[k] * C_);
            const float wk = w[k];
#pragma unroll
            for (int i = 0; i < 8; ++i) {
                const float4 v = f[i];
                acc[i].x += wk * v.x;
                acc[i].y += wk * v.y;
                acc[i].z += wk * v.z;
                acc[i].w += wk * v.w;
            }
        }
    } else {
        float* accf = reinterpret_cast<float*>(acc);
#pragma unroll
        for (int k = 0; k < K_; ++k) {
            const float wk = w[k];
#pragma unroll
            for (int c = 0; c < C_; ++c) {
                accf[c] += wk * pt[(size_t)c * P_ + idx[k]];
            }
        }
    }

    // Write 32 channels; for fixed c adjacent lanes (adjacent w) are
    // contiguous -> every store instruction is fully coalesced.
    const float* accf = reinterpret_cast<const float*>(acc);
    const size_t obase = (size_t)n * C_ * HW_ + hw;
#pragma unroll
    for (int c = 0; c < C_; ++c) {
        out[obase + (size_t)c * HW_] = accf[c];
    }
}

// ---------------------------------------------------------------------------
extern "C" void kernel_launch(void* const* d_in, const int* in_sizes, int n_in,
                              void* d_out, int out_size, void* d_ws, size_t ws_size,
                              hipStream_t stream)
{
    const int*   frags  = (const int*)  d_in[0];   // fragments (int)
    const float* alphas = (const float*)d_in[1];   // alphas f32
    const float* ptclds = (const float*)d_in[2];   // ptclds (C,P) f32
    float*       out    = (float*)      d_out;     // (N,C,H,W) f32

    const size_t needed = (size_t)P_ * C_ * sizeof(float);  // 25.6 MB

    const int total_px  = N_ * HW_;                // 262144
    const int cblocks   = total_px / 256;          // 1024

    if (ws_size >= needed) {
        float* ptT = (float*)d_ws;                 // (P,C)
        dim3 tb(32, 8);
        transpose_ptclds_kernel<<<P_ / 32, tb, 0, stream>>>(ptclds, ptT);
        composite_kernel<true><<<cblocks, 256, 0, stream>>>(frags, alphas, ptT, out);
    } else {
        composite_kernel<false><<<cblocks, 256, 0, stream>>>(frags, alphas, ptclds, out);
    }
}

// Round 3
// 128.844 us; speedup vs baseline: 1.1517x; 1.1517x over previous
//
#include <hip/hip_runtime.h>

// AlphaCompositor: fragments (N,K,H,W) int32 indices (-1 = empty),
// alphas (N,K,H,W) f32, ptclds (C,P) f32 -> images (N,C,H,W) f32.
// N=4 K=8 H=W=256 C=32 P=200000.

#define N_  4
#define K_  8
#define H_  256
#define W_  256
#define C_  32
#define P_  200000
#define HW_ (H_ * W_)

// ---------------------------------------------------------------------------
// Kernel 1: transpose ptclds (C,P) -> (P,C), fully vectorized (float4 in,
// LDS tile, float4 out). Tile = 64 points x 32 channels (8 KB + pad).
// P = 200000 = 3125 * 64 exactly.
// ---------------------------------------------------------------------------
__global__ __launch_bounds__(256) void transpose_ptclds_kernel(
    const float* __restrict__ src,   // (C_, P_)
    float*       __restrict__ dst)   // (P_, C_)
{
    __shared__ float tile[32][65];   // +1 pad breaks row-bank aliasing
    const int p0 = blockIdx.x * 64;
    const int t  = threadIdx.x;

    // Load 64 pts x 32 ch = 512 float4 along P. Per wave: 4 channel-rows,
    // 256 B contiguous each -> fully coalesced dwordx4.
#pragma unroll
    for (int i = 0; i < 2; ++i) {
        const int e  = i * 256 + t;
        const int c  = e >> 4;          // 0..31
        const int pg = e & 15;          // 0..15 (x4 points)
        const float4 v = *reinterpret_cast<const float4*>(
            src + (size_t)c * P_ + p0 + pg * 4);
        tile[c][pg * 4 + 0] = v.x;
        tile[c][pg * 4 + 1] = v.y;
        tile[c][pg * 4 + 2] = v.z;
        tile[c][pg * 4 + 3] = v.w;
    }
    __syncthreads();

    // Store 64 pts x 8 channel-quads = 512 float4 along C. Per wave:
    // 8 points x 128 B = 1 KB contiguous -> fully coalesced dwordx4.
#pragma unroll
    for (int i = 0; i < 2; ++i) {
        const int e  = i * 256 + t;
        const int p  = e >> 3;          // 0..63
        const int cc = e & 7;           // 0..7 (x4 channels)
        float4 v;
        v.x = tile[cc * 4 + 0][p];
        v.y = tile[cc * 4 + 1][p];
        v.z = tile[cc * 4 + 2][p];
        v.w = tile[cc * 4 + 3][p];
        *reinterpret_cast<float4*>(dst + (size_t)(p0 + p) * C_ + cc * 4) = v;
    }
}

// ---------------------------------------------------------------------------
// Kernel 2: composite, cooperative gather. 8 lanes per pixel; lane owns 4
// channels (one float4 of the point's 128 B feature row). One gather
// instruction touches 8 cache lines (one per pixel in the wave) instead of
// 64 -> ~8x less TCP address-processing; 2M threads -> full occupancy.
// ---------------------------------------------------------------------------
template <bool TRANSPOSED>
__global__ __launch_bounds__(256) void composite_kernel(
    const int*   __restrict__ frags,   // (N,K,H,W)
    const float* __restrict__ alphas,  // (N,K,H,W)
    const float* __restrict__ pt,      // (P,C) if TRANSPOSED else (C,P)
    float*       __restrict__ out)     // (N,C,H,W)
{
    const int tid = blockIdx.x * blockDim.x + threadIdx.x;  // 0 .. N*HW*8-1
    const int gid = tid >> 3;          // pixel id, 0 .. N*HW-1
    const int cg  = tid & 7;           // channel quad 0..7 (lane's 4 channels)
    const int n   = gid >> 16;         // HW_ == 65536
    const int hw  = gid & (HW_ - 1);
    const int base = n * K_ * HW_ + hw;

    // 8 indices + 8 alphas. Within an 8-lane pixel-group the addresses are
    // identical (broadcast); across the wave they span 32 contiguous bytes
    // -> each load instruction touches a single cache line.
    int   idx[K_];
    float al[K_];
#pragma unroll
    for (int k = 0; k < K_; ++k) idx[k] = frags[base + k * HW_];
#pragma unroll
    for (int k = 0; k < K_; ++k) al[k] = alphas[base + k * HW_];

    // Exclusive-transmittance weights (redundant across the 8 lanes; VALU
    // is nearly idle so this is free).
    float w[K_];
    float T = 1.0f;
#pragma unroll
    for (int k = 0; k < K_; ++k) {
        const bool valid = idx[k] >= 0;
        const float a = valid ? al[k] : 0.0f;
        w[k] = a * T;
        T *= (1.0f - a);
        if (!valid) idx[k] = 0;
    }

    float4 acc = make_float4(0.f, 0.f, 0.f, 0.f);

    if (TRANSPOSED) {
#pragma unroll
        for (int k = 0; k < K_; ++k) {
            const float4 v = *reinterpret_cast<const float4*>(
                pt + (size_t)idx[k] * C_ + cg * 4);
            const float wk = w[k];
            acc.x += wk * v.x;
            acc.y += wk * v.y;
            acc.z += wk * v.z;
            acc.w += wk * v.w;
        }
    } else {
        // Fallback: gather from (C,P) layout (scalar, slow but correct).
#pragma unroll
        for (int k = 0; k < K_; ++k) {
            const float wk = w[k];
#pragma unroll
            for (int j = 0; j < 4; ++j) {
                acc.x = (j == 0) ? acc.x + wk * pt[(size_t)(cg * 4 + 0) * P_ + idx[k]] : acc.x;
            }
            acc.y += wk * pt[(size_t)(cg * 4 + 1) * P_ + idx[k]];
            acc.z += wk * pt[(size_t)(cg * 4 + 2) * P_ + idx[k]];
            acc.w += wk * pt[(size_t)(cg * 4 + 3) * P_ + idx[k]];
        }
    }

    // Store 4 channels. Per store instruction: 8 channel-planes x 32 B
    // contiguous chunks -> 8 cache lines per wave, fully utilized.
    const size_t obase = (size_t)n * C_ * HW_ + hw;
    out[obase + (size_t)(cg * 4 + 0) * HW_] = acc.x;
    out[obase + (size_t)(cg * 4 + 1) * HW_] = acc.y;
    out[obase + (size_t)(cg * 4 + 2) * HW_] = acc.z;
    out[obase + (size_t)(cg * 4 + 3) * HW_] = acc.w;
}

// ---------------------------------------------------------------------------
extern "C" void kernel_launch(void* const* d_in, const int* in_sizes, int n_in,
                              void* d_out, int out_size, void* d_ws, size_t ws_size,
                              hipStream_t stream)
{
    const int*   frags  = (const int*)  d_in[0];   // fragments (int)
    const float* alphas = (const float*)d_in[1];   // alphas f32
    const float* ptclds = (const float*)d_in[2];   // ptclds (C,P) f32
    float*       out    = (float*)      d_out;     // (N,C,H,W) f32

    const size_t needed = (size_t)P_ * C_ * sizeof(float);  // 25.6 MB

    const int total_thr = N_ * HW_ * 8;            // 2,097,152
    const int cblocks   = total_thr / 256;         // 8192

    if (ws_size >= needed) {
        float* ptT = (float*)d_ws;                 // (P,C)
        transpose_ptclds_kernel<<<P_ / 64, 256, 0, stream>>>(ptclds, ptT);
        composite_kernel<true><<<cblocks, 256, 0, stream>>>(frags, alphas, ptT, out);
    } else {
        composite_kernel<false><<<cblocks, 256, 0, stream>>>(frags, alphas, ptclds, out);
    }
}

// Round 4
// 122.399 us; speedup vs baseline: 1.2123x; 1.0527x over previous
//
#include <hip/hip_runtime.h>

// AlphaCompositor: fragments (N,K,H,W) int32 indices (-1 = empty),
// alphas (N,K,H,W) f32, ptclds (C,P) f32 -> images (N,C,H,W) f32.
// N=4 K=8 H=W=256 C=32 P=200000.
//
// Strategy: transpose+downconvert ptclds (C,P) f32 -> (P,C) fp16 (12.8 MB,
// 2x better L2 residency, half the gather bytes), then composite with
// 4 lanes/pixel, each lane gathering one 16 B half8 (8 channels).

#define N_  4
#define K_  8
#define H_  256
#define W_  256
#define C_  32
#define P_  200000
#define HW_ (H_ * W_)

typedef _Float16 half8_t __attribute__((ext_vector_type(8)));  // 16 B

// ---------------------------------------------------------------------------
// Kernel 1: transpose ptclds (C,P) f32 -> (P,C) fp16.
// Tile = 64 points x 32 channels. P = 200000 = 3125 * 64 exactly.
// Loads: float4, 256 B contiguous per channel-row per wave (coalesced).
// Stores: half8 (16 B/lane), 1 KB contiguous per wave (coalesced).
// ---------------------------------------------------------------------------
__global__ __launch_bounds__(256) void transpose_ptclds_kernel(
    const float*  __restrict__ src,   // (C_, P_) f32
    _Float16*     __restrict__ dst)   // (P_, C_) fp16
{
    __shared__ float tile[32][65];   // +1 pad: conflict-free transpose
    const int p0 = blockIdx.x * 64;
    const int t  = threadIdx.x;

#pragma unroll
    for (int i = 0; i < 2; ++i) {
        const int e  = i * 256 + t;
        const int c  = e >> 4;          // 0..31
        const int pg = e & 15;          // 0..15 (x4 points)
        const float4 v = *reinterpret_cast<const float4*>(
            src + (size_t)c * P_ + p0 + pg * 4);
        tile[c][pg * 4 + 0] = v.x;
        tile[c][pg * 4 + 1] = v.y;
        tile[c][pg * 4 + 2] = v.z;
        tile[c][pg * 4 + 3] = v.w;
    }
    __syncthreads();

    const int p = t >> 2;               // 0..63 (point within tile)
    const int q = t & 3;                // 0..3  (channel octet)
    half8_t h;
#pragma unroll
    for (int j = 0; j < 8; ++j) h[j] = (_Float16)tile[q * 8 + j][p];
    *reinterpret_cast<half8_t*>(dst + (size_t)(p0 + p) * C_ + q * 8) = h;
}

// ---------------------------------------------------------------------------
// Kernel 2: composite. 4 lanes per pixel; lane owns 8 channels (one 16 B
// half8 of the point's 64 B fp16 feature row). Per gather instruction a
// wave touches 16 distinct 64 B rows -> full dwordx4 width, minimal TCP
// cycles. 1 M threads -> full latency hiding.
// ---------------------------------------------------------------------------
template <bool TRANSPOSED>
__global__ __launch_bounds__(256) void composite_kernel(
    const int*   __restrict__ frags,   // (N,K,H,W) int32
    const float* __restrict__ alphas,  // (N,K,H,W) f32
    const void*  __restrict__ pt,      // (P,C) fp16 if TRANSPOSED else (C,P) f32
    float*       __restrict__ out)     // (N,C,H,W) f32
{
    const int tid = blockIdx.x * blockDim.x + threadIdx.x;  // 0 .. N*HW*4-1
    const int gid = tid >> 2;          // pixel id
    const int cg  = tid & 3;           // channel octet 0..3
    const int n   = gid >> 16;         // HW_ == 65536
    const int hw  = gid & (HW_ - 1);
    const int base = n * K_ * HW_ + hw;

    // 8 indices + 8 alphas; 4-way redundant across the pixel's lanes but a
    // wave's lanes span 16 consecutive hw -> one 64 B line per instruction.
    int   idx[K_];
    float al[K_];
#pragma unroll
    for (int k = 0; k < K_; ++k) idx[k] = frags[base + k * HW_];
#pragma unroll
    for (int k = 0; k < K_; ++k) al[k] = alphas[base + k * HW_];

    // Exclusive-transmittance compositing weights (K=8, sequential, cheap).
    float w[K_];
    float T = 1.0f;
#pragma unroll
    for (int k = 0; k < K_; ++k) {
        const bool valid = idx[k] >= 0;
        const float a = valid ? al[k] : 0.0f;
        w[k] = a * T;
        T *= (1.0f - a);
        if (!valid) idx[k] = 0;        // safe gather; weight is 0
    }

    float acc[8];
#pragma unroll
    for (int j = 0; j < 8; ++j) acc[j] = 0.0f;

    if (TRANSPOSED) {
        const _Float16* tp = (const _Float16*)pt;
#pragma unroll
        for (int k = 0; k < K_; ++k) {
            const half8_t v = *reinterpret_cast<const half8_t*>(
                tp + (size_t)idx[k] * C_ + cg * 8);
            const float wk = w[k];
#pragma unroll
            for (int j = 0; j < 8; ++j) acc[j] += wk * (float)v[j];
        }
    } else {
        // Fallback: gather from original (C,P) f32 layout (slow but correct).
        const float* fp = (const float*)pt;
#pragma unroll
        for (int k = 0; k < K_; ++k) {
            const float wk = w[k];
#pragma unroll
            for (int j = 0; j < 8; ++j)
                acc[j] += wk * fp[(size_t)(cg * 8 + j) * P_ + idx[k]];
        }
    }

    // Store 8 channels; per instruction a wave writes 4 channel planes x
    // 64 B contiguous (16 consecutive pixels) -> fully coalesced.
    const size_t obase = (size_t)n * C_ * HW_ + hw;
#pragma unroll
    for (int j = 0; j < 8; ++j)
        out[obase + (size_t)(cg * 8 + j) * HW_] = acc[j];
}

// ---------------------------------------------------------------------------
extern "C" void kernel_launch(void* const* d_in, const int* in_sizes, int n_in,
                              void* d_out, int out_size, void* d_ws, size_t ws_size,
                              hipStream_t stream)
{
    const int*   frags  = (const int*)  d_in[0];
    const float* alphas = (const float*)d_in[1];
    const float* ptclds = (const float*)d_in[2];   // (C,P) f32
    float*       out    = (float*)      d_out;     // (N,C,H,W) f32

    const size_t needed = (size_t)P_ * C_ * sizeof(_Float16);  // 12.8 MB

    const int total_thr = N_ * HW_ * 4;            // 1,048,576
    const int cblocks   = total_thr / 256;         // 4096

    if (ws_size >= needed) {
        _Float16* ptT = (_Float16*)d_ws;           // (P,C) fp16
        transpose_ptclds_kernel<<<P_ / 64, 256, 0, stream>>>(ptclds, ptT);
        composite_kernel<true><<<cblocks, 256, 0, stream>>>(frags, alphas, ptT, out);
    } else {
        composite_kernel<false><<<cblocks, 256, 0, stream>>>(frags, alphas, ptclds, out);
    }
}

// Round 5
// 121.378 us; speedup vs baseline: 1.2225x; 1.0084x over previous
//
#include <hip/hip_runtime.h>

// AlphaCompositor: fragments (N,K,H,W) int32 indices (-1 = empty),
// alphas (N,K,H,W) f32, ptclds (C,P) f32 -> images (N,C,H,W) f32.
// N=4 K=8 H=W=256 C=32 P=200000.
//
// Strategy: transpose+downconvert ptclds (C,P) f32 -> (P,C) fp16 (12.8 MB),
// then composite with 4 lanes/pixel, each lane gathering one 16 B half8
// (8 channels). This round: force all K=8 gathers into a live register
// array BEFORE consuming (VGPR 28 -> ~70) so 8 loads are in flight per
// thread instead of ~2 (gather-latency bound -> fix MLP).

#define N_  4
#define K_  8
#define H_  256
#define W_  256
#define C_  32
#define P_  200000
#define HW_ (H_ * W_)

typedef _Float16 half8_t __attribute__((ext_vector_type(8)));  // 16 B

// ---------------------------------------------------------------------------
// Kernel 1: transpose ptclds (C,P) f32 -> (P,C) fp16.
// Tile = 64 points x 32 channels. P = 200000 = 3125 * 64 exactly.
// ---------------------------------------------------------------------------
__global__ __launch_bounds__(256) void transpose_ptclds_kernel(
    const float*  __restrict__ src,   // (C_, P_) f32
    _Float16*     __restrict__ dst)   // (P_, C_) fp16
{
    __shared__ float tile[32][65];   // +1 pad: conflict-free transpose
    const int p0 = blockIdx.x * 64;
    const int t  = threadIdx.x;

#pragma unroll
    for (int i = 0; i < 2; ++i) {
        const int e  = i * 256 + t;
        const int c  = e >> 4;          // 0..31
        const int pg = e & 15;          // 0..15 (x4 points)
        const float4 v = *reinterpret_cast<const float4*>(
            src + (size_t)c * P_ + p0 + pg * 4);
        tile[c][pg * 4 + 0] = v.x;
        tile[c][pg * 4 + 1] = v.y;
        tile[c][pg * 4 + 2] = v.z;
        tile[c][pg * 4 + 3] = v.w;
    }
    __syncthreads();

    const int p = t >> 2;               // 0..63 (point within tile)
    const int q = t & 3;                // 0..3  (channel octet)
    half8_t h;
#pragma unroll
    for (int j = 0; j < 8; ++j) h[j] = (_Float16)tile[q * 8 + j][p];
    *reinterpret_cast<half8_t*>(dst + (size_t)(p0 + p) * C_ + q * 8) = h;
}

// ---------------------------------------------------------------------------
// Kernel 2: composite. 4 lanes per pixel; lane owns 8 channels (one 16 B
// half8 of the point's 64 B fp16 feature row). All 8 gathers issued into
// a live register array before any consumption -> MLP=8 per thread.
// ---------------------------------------------------------------------------
template <bool TRANSPOSED>
__global__ __launch_bounds__(256) void composite_kernel(
    const int*   __restrict__ frags,   // (N,K,H,W) int32
    const float* __restrict__ alphas,  // (N,K,H,W) f32
    const void*  __restrict__ pt,      // (P,C) fp16 if TRANSPOSED else (C,P) f32
    float*       __restrict__ out)     // (N,C,H,W) f32
{
    const int tid = blockIdx.x * blockDim.x + threadIdx.x;  // 0 .. N*HW*4-1
    const int gid = tid >> 2;          // pixel id
    const int cg  = tid & 3;           // channel octet 0..3
    const int n   = gid >> 16;         // HW_ == 65536
    const int hw  = gid & (HW_ - 1);
    const int base = n * K_ * HW_ + hw;

    // 8 indices + 8 alphas (one 64 B line per instruction across the wave).
    int   idx[K_];
    float al[K_];
#pragma unroll
    for (int k = 0; k < K_; ++k) idx[k] = frags[base + k * HW_];
#pragma unroll
    for (int k = 0; k < K_; ++k) al[k] = alphas[base + k * HW_];

    // Exclusive-transmittance compositing weights (K=8, sequential, cheap).
    float w[K_];
    float T = 1.0f;
#pragma unroll
    for (int k = 0; k < K_; ++k) {
        const bool valid = idx[k] >= 0;
        const float a = valid ? al[k] : 0.0f;
        w[k] = a * T;
        T *= (1.0f - a);
        if (!valid) idx[k] = 0;        // safe gather; weight is 0
    }

    float acc[8];
#pragma unroll
    for (int j = 0; j < 8; ++j) acc[j] = 0.0f;

    if (TRANSPOSED) {
        const _Float16* tp = (const _Float16*)pt;
        // Phase 1: issue ALL 8 independent gathers into live registers.
        half8_t v[K_];
#pragma unroll
        for (int k = 0; k < K_; ++k) {
            v[k] = *reinterpret_cast<const half8_t*>(
                tp + (size_t)idx[k] * C_ + cg * 8);
        }
        // Phase 2: consume.
#pragma unroll
        for (int k = 0; k < K_; ++k) {
            const float wk = w[k];
#pragma unroll
            for (int j = 0; j < 8; ++j) acc[j] += wk * (float)v[k][j];
        }
    } else {
        // Fallback: gather from original (C,P) f32 layout (slow but correct).
        const float* fp = (const float*)pt;
#pragma unroll
        for (int k = 0; k < K_; ++k) {
            const float wk = w[k];
#pragma unroll
            for (int j = 0; j < 8; ++j)
                acc[j] += wk * fp[(size_t)(cg * 8 + j) * P_ + idx[k]];
        }
    }

    // Store 8 channels; per instruction a wave writes 4 channel planes x
    // 64 B contiguous (16 consecutive pixels) -> fully coalesced.
    const size_t obase = (size_t)n * C_ * HW_ + hw;
#pragma unroll
    for (int j = 0; j < 8; ++j)
        out[obase + (size_t)(cg * 8 + j) * HW_] = acc[j];
}

// ---------------------------------------------------------------------------
extern "C" void kernel_launch(void* const* d_in, const int* in_sizes, int n_in,
                              void* d_out, int out_size, void* d_ws, size_t ws_size,
                              hipStream_t stream)
{
    const int*   frags  = (const int*)  d_in[0];
    const float* alphas = (const float*)d_in[1];
    const float* ptclds = (const float*)d_in[2];   // (C,P) f32
    float*       out    = (float*)      d_out;     // (N,C,H,W) f32

    const size_t needed = (size_t)P_ * C_ * sizeof(_Float16);  // 12.8 MB

    const int total_thr = N_ * HW_ * 4;            // 1,048,576
    const int cblocks   = total_thr / 256;         // 4096

    if (ws_size >= needed) {
        _Float16* ptT = (_Float16*)d_ws;           // (P,C) fp16
        transpose_ptclds_kernel<<<P_ / 64, 256, 0, stream>>>(ptclds, ptT);
        composite_kernel<true><<<cblocks, 256, 0, stream>>>(frags, alphas, ptT, out);
    } else {
        composite_kernel<false><<<cblocks, 256, 0, stream>>>(frags, alphas, ptclds, out);
    }
}

// Round 9
// 120.577 us; speedup vs baseline: 1.2306x; 1.0066x over previous
//
#include <hip/hip_runtime.h>

// AlphaCompositor: fragments (N,K,H,W) int32 indices (-1 = empty),
// alphas (N,K,H,W) f32, ptclds (C,P) f32 -> images (N,C,H,W) f32.
// N=4 K=8 H=W=256 C=32 P=200000.
//
// Strategy: transpose+downconvert ptclds (C,P) f32 -> (P,C) fp16 (12.8 MB),
// then block-cooperative composite: 64 pixels/block, frag+alpha staged to
// LDS via wide coalesced loads (vmem instrs 32 -> 20 per thread), 4 lanes
// per pixel each gathering one 16 B half8 (8 channels).

#define N_  4
#define K_  8
#define H_  256
#define W_  256
#define C_  32
#define P_  200000
#define HW_ (H_ * W_)

typedef _Float16 half8_t __attribute__((ext_vector_type(8)));  // 16 B

// ---------------------------------------------------------------------------
// Kernel 1: transpose ptclds (C,P) f32 -> (P,C) fp16.
// Tile = 64 points x 32 channels. P = 200000 = 3125 * 64 exactly.
// ---------------------------------------------------------------------------
__global__ __launch_bounds__(256) void transpose_ptclds_kernel(
    const float*  __restrict__ src,   // (C_, P_) f32
    _Float16*     __restrict__ dst)   // (P_, C_) fp16
{
    __shared__ float tile[32][65];   // +1 pad: conflict-free transpose
    const int p0 = blockIdx.x * 64;
    const int t  = threadIdx.x;

#pragma unroll
    for (int i = 0; i < 2; ++i) {
        const int e  = i * 256 + t;
        const int c  = e >> 4;          // 0..31
        const int pg = e & 15;          // 0..15 (x4 points)
        const float4 v = *reinterpret_cast<const float4*>(
            src + (size_t)c * P_ + p0 + pg * 4);
        tile[c][pg * 4 + 0] = v.x;
        tile[c][pg * 4 + 1] = v.y;
        tile[c][pg * 4 + 2] = v.z;
        tile[c][pg * 4 + 3] = v.w;
    }
    __syncthreads();

    const int p = t >> 2;               // 0..63 (point within tile)
    const int q = t & 3;                // 0..3  (channel octet)
    half8_t h;
#pragma unroll
    for (int j = 0; j < 8; ++j) h[j] = (_Float16)tile[q * 8 + j][p];
    *reinterpret_cast<half8_t*>(dst + (size_t)(p0 + p) * C_ + q * 8) = h;
}

// ---------------------------------------------------------------------------
// Kernel 2: block-cooperative composite. 64 pixels per 256-thread block.
// Phase 1: stage 64x8 frag+alpha into LDS (2+2 coalesced dword loads/thread,
//          4 full cache lines per wave instruction).
// Phase 2: thread = (pixel, channel-octet). Weights recomputed per-thread
//          from LDS broadcast reads (conflict-free); 8 register-resident
//          half8 gathers; 8 coalesced dword stores.
// ---------------------------------------------------------------------------
template <bool TRANSPOSED>
__global__ __launch_bounds__(256) void composite_kernel(
    const int*   __restrict__ frags,   // (N,K,H,W) int32
    const float* __restrict__ alphas,  // (N,K,H,W) f32
    const void*  __restrict__ pt,      // (P,C) fp16 if TRANSPOSED else (C,P) f32
    float*       __restrict__ out)     // (N,C,H,W) f32
{
    __shared__ int   s_idx[K_][64];
    __shared__ float s_al [K_][64];

    const int t    = threadIdx.x;
    const int gid0 = blockIdx.x * 64;        // first pixel of block
    const int n    = gid0 >> 16;             // HW_ == 65536; 64 | HW_ so no straddle
    const int hw0  = gid0 & (HW_ - 1);
    const int base = n * K_ * HW_ + hw0;

    // Phase 1: cooperative staging, fully coalesced.
#pragma unroll
    for (int i = 0; i < 2; ++i) {
        const int e = i * 256 + t;           // 0..511
        const int k = e >> 6;                // 0..7
        const int p = e & 63;                // 0..63
        s_idx[k][p] = frags [base + k * HW_ + p];
        s_al [k][p] = alphas[base + k * HW_ + p];
    }
    __syncthreads();

    const int p  = t >> 2;                   // pixel within block, 0..63
    const int og = t & 3;                    // channel octet 0..3

    // Weights: exclusive-transmittance scan over K=8. Redundant x4 across
    // the pixel's lanes; LDS reads are 4-way same-address broadcast (free).
    int   idx[K_];
    float w  [K_];
    float T = 1.0f;
#pragma unroll
    for (int k = 0; k < K_; ++k) {
        const int  ix    = s_idx[k][p];
        const bool valid = ix >= 0;
        const float a = valid ? s_al[k][p] : 0.0f;
        w[k] = a * T;
        T *= (1.0f - a);
        idx[k] = valid ? ix : 0;             // safe gather; weight is 0
    }

    float acc[8];
#pragma unroll
    for (int j = 0; j < 8; ++j) acc[j] = 0.0f;

    if (TRANSPOSED) {
        const _Float16* tp = (const _Float16*)pt;
        // All 8 independent gathers in flight before consumption (MLP=8).
        half8_t v[K_];
#pragma unroll
        for (int k = 0; k < K_; ++k) {
            v[k] = *reinterpret_cast<const half8_t*>(
                tp + (size_t)idx[k] * C_ + og * 8);
        }
#pragma unroll
        for (int k = 0; k < K_; ++k) {
            const float wk = w[k];
#pragma unroll
            for (int j = 0; j < 8; ++j) acc[j] += wk * (float)v[k][j];
        }
    } else {
        // Fallback: gather from original (C,P) f32 layout (slow but correct).
        const float* fp = (const float*)pt;
#pragma unroll
        for (int k = 0; k < K_; ++k) {
            const float wk = w[k];
#pragma unroll
            for (int j = 0; j < 8; ++j)
                acc[j] += wk * fp[(size_t)(og * 8 + j) * P_ + idx[k]];
        }
    }

    // Stores: per instruction the wave writes 4 channel planes x 64 B
    // contiguous (16 consecutive pixels) -> fully coalesced.
    const size_t obase = (size_t)n * C_ * HW_ + hw0 + p;
#pragma unroll
    for (int j = 0; j < 8; ++j)
        out[obase + (size_t)(og * 8 + j) * HW_] = acc[j];
}

// ---------------------------------------------------------------------------
extern "C" void kernel_launch(void* const* d_in, const int* in_sizes, int n_in,
                              void* d_out, int out_size, void* d_ws, size_t ws_size,
                              hipStream_t stream)
{
    const int*   frags  = (const int*)  d_in[0];
    const float* alphas = (const float*)d_in[1];
    const float* ptclds = (const float*)d_in[2];   // (C,P) f32
    float*       out    = (float*)      d_out;     // (N,C,H,W) f32

    const size_t needed = (size_t)P_ * C_ * sizeof(_Float16);  // 12.8 MB

    const int total_px = N_ * HW_;                 // 262144
    const int cblocks  = total_px / 64;            // 4096 blocks x 256 thr

    if (ws_size >= needed) {
        _Float16* ptT = (_Float16*)d_ws;           // (P,C) fp16
        transpose_ptclds_kernel<<<P_ / 64, 256, 0, stream>>>(ptclds, ptT);
        composite_kernel<true><<<cblocks, 256, 0, stream>>>(frags, alphas, ptT, out);
    } else {
        composite_kernel<false><<<cblocks, 256, 0, stream>>>(frags, alphas, ptclds, out);
    }
}